// Round 1
// baseline (933.493 us; speedup 1.0000x reference)
//
#include <hip/hip_runtime.h>
#include <hip/hip_bf16.h>
#include <stdint.h>

#define B_ 16
#define H_ 128
#define W_ 128
#define C_ 128
#define F_ 64
#define N_ (H_*W_)          // 16384
#define SPLITS 32
#define RPB (N_/SPLITS)     // 512 rows per block
#define CHUNK 16
#define EPSV 1e-3f

__device__ __forceinline__ unsigned short f2b(float f) {
    unsigned int x = __float_as_uint(f);
    x += 0x7fffu + ((x >> 16) & 1u);
    return (unsigned short)(x >> 16);
}
__device__ __forceinline__ float b2f(unsigned short u) {
    return __uint_as_float(((unsigned int)u) << 16);
}

// Kernel A: per-split S = X^T X partials + column sums + g = X@Wg + bg (bf16)
__global__ __launch_bounds__(256, 2)
void kA(const float* __restrict__ x, const float* __restrict__ Wg,
        const float* __restrict__ bg, unsigned short* __restrict__ g,
        float* __restrict__ Spart, float* __restrict__ cspart)
{
    __shared__ float xs[CHUNK][C_ + 4];   // +4 pad breaks g-phase row conflicts
    __shared__ float wgs[C_][F_];

    const int tid = threadIdx.x;
    const int b  = blockIdx.x / SPLITS;
    const int sp = blockIdx.x % SPLITS;

    for (int t = tid; t < (C_*F_)/4; t += 256)
        ((float4*)wgs)[t] = ((const float4*)Wg)[t];

    const int tr = tid >> 4;        // 0..15  (S rows tile)
    const int tc = tid & 15;        // 0..15  (S cols tile)
    const int gr = tid >> 4;        // g row within chunk
    const int gc = (tid & 15) * 4;  // g col base

    const float4 bgv = *(const float4*)(bg + gc);

    const float* xb = x + ((size_t)b * N_ + (size_t)sp * RPB) * C_;
    unsigned short* gb = g + ((size_t)b * N_ + (size_t)sp * RPB) * F_;

    float acc[8][8];
    for (int i = 0; i < 8; ++i)
        for (int j = 0; j < 8; ++j) acc[i][j] = 0.f;
    float cs8[8] = {0.f,0.f,0.f,0.f,0.f,0.f,0.f,0.f};

    for (int ch = 0; ch < RPB/CHUNK; ++ch) {
        const float4* src = (const float4*)(xb + (size_t)ch * CHUNK * C_);
        float4 v0 = src[tid];
        float4 v1 = src[tid + 256];
        __syncthreads();             // prior chunk's readers done
        {
            int e0 = tid * 4;
            *(float4*)&xs[e0 >> 7][e0 & 127] = v0;
            int e1 = e0 + 1024;
            *(float4*)&xs[e1 >> 7][e1 & 127] = v1;
        }
        __syncthreads();

        // S phase: 8x8 register tile rank-CHUNK update
        for (int r = 0; r < CHUNK; ++r) {
            float a0[8], b0[8];
            *(float4*)&a0[0] = *(const float4*)&xs[r][tr*8];
            *(float4*)&a0[4] = *(const float4*)&xs[r][tr*8+4];
            *(float4*)&b0[0] = *(const float4*)&xs[r][tc*8];
            *(float4*)&b0[4] = *(const float4*)&xs[r][tc*8+4];
            for (int i = 0; i < 8; ++i)
                for (int j = 0; j < 8; ++j)
                    acc[i][j] = fmaf(a0[i], b0[j], acc[i][j]);
            if (tc == 0)
                for (int i = 0; i < 8; ++i) cs8[i] += a0[i];
        }

        // g phase: row gr, 4 cols gc..gc+3
        {
            float s0=0.f, s1=0.f, s2=0.f, s3=0.f;
            #pragma unroll 8
            for (int k = 0; k < C_; k += 4) {
                float4 xv = *(const float4*)&xs[gr][k];
                float4 w0 = *(const float4*)&wgs[k+0][gc];
                float4 w1 = *(const float4*)&wgs[k+1][gc];
                float4 w2 = *(const float4*)&wgs[k+2][gc];
                float4 w3 = *(const float4*)&wgs[k+3][gc];
                s0 = fmaf(xv.x, w0.x, s0); s1 = fmaf(xv.x, w0.y, s1); s2 = fmaf(xv.x, w0.z, s2); s3 = fmaf(xv.x, w0.w, s3);
                s0 = fmaf(xv.y, w1.x, s0); s1 = fmaf(xv.y, w1.y, s1); s2 = fmaf(xv.y, w1.z, s2); s3 = fmaf(xv.y, w1.w, s3);
                s0 = fmaf(xv.z, w2.x, s0); s1 = fmaf(xv.z, w2.y, s1); s2 = fmaf(xv.z, w2.z, s2); s3 = fmaf(xv.z, w2.w, s3);
                s0 = fmaf(xv.w, w3.x, s0); s1 = fmaf(xv.w, w3.y, s1); s2 = fmaf(xv.w, w3.z, s2); s3 = fmaf(xv.w, w3.w, s3);
            }
            ushort4 o;
            o.x = f2b(s0 + bgv.x);
            o.y = f2b(s1 + bgv.y);
            o.z = f2b(s2 + bgv.z);
            o.w = f2b(s3 + bgv.w);
            *(ushort4*)(gb + ((size_t)(ch*CHUNK + gr)) * F_ + gc) = o;
        }
    }

    float* so = Spart + ((size_t)(b * SPLITS + sp)) * (size_t)(C_ * C_);
    for (int i = 0; i < 8; ++i) {
        float4 q0 = make_float4(acc[i][0], acc[i][1], acc[i][2], acc[i][3]);
        float4 q1 = make_float4(acc[i][4], acc[i][5], acc[i][6], acc[i][7]);
        *(float4*)(so + (size_t)(tr*8+i)*C_ + tc*8)     = q0;
        *(float4*)(so + (size_t)(tr*8+i)*C_ + tc*8 + 4) = q1;
    }
    if (tc == 0) {
        float* co = cspart + ((size_t)(b * SPLITS + sp)) * C_;
        for (int i = 0; i < 8; ++i) co[tr*8+i] = cs8[i];
    }
}

// Kernel B: reduce partials; fm = Wt^T S Wp + bias terms; softmax rows -> U
__global__ __launch_bounds__(256, 1)
void kB(const float* __restrict__ Spart, const float* __restrict__ cspart,
        const float* __restrict__ Wt, const float* __restrict__ bt,
        const float* __restrict__ Wp, const float* __restrict__ bp,
        float* __restrict__ U)
{
    __shared__ float S[C_][C_];     // 64 KiB
    __shared__ float T1[C_][F_];    // 32 KiB
    __shared__ float fmb[F_][F_];   // 16 KiB
    __shared__ float cs[C_];
    __shared__ float T2[F_];
    __shared__ float T3[F_];

    const int tid = threadIdx.x;
    const int b = blockIdx.x;

    const float* sp0 = Spart + (size_t)b * SPLITS * C_ * C_;
    for (int idx = tid; idx < C_*C_; idx += 256) {
        float s = 0.f;
        for (int k = 0; k < SPLITS; ++k) s += sp0[(size_t)k * C_ * C_ + idx];
        ((float*)S)[idx] = s;
    }
    if (tid < C_) {
        const float* cp0 = cspart + (size_t)b * SPLITS * C_ + tid;
        float s = 0.f;
        for (int k = 0; k < SPLITS; ++k) s += cp0[(size_t)k * C_];
        cs[tid] = s;
    }
    __syncthreads();

    // T1 = S @ Wp   [128][64]
    for (int idx = tid; idx < C_*F_; idx += 256) {
        int c = idx >> 6, j = idx & 63;
        float s = 0.f;
        for (int k = 0; k < C_; ++k) s = fmaf(S[c][k], Wp[k*F_ + j], s);
        T1[c][j] = s;
    }
    if (tid < F_) {
        float s = 0.f;
        for (int k = 0; k < C_; ++k) s = fmaf(cs[k], Wp[k*F_ + tid], s);
        T2[tid] = s;
    } else if (tid < 2*F_) {
        int i = tid - F_;
        float s = 0.f;
        for (int k = 0; k < C_; ++k) s = fmaf(cs[k], Wt[k*F_ + i], s);
        T3[i] = s;
    }
    __syncthreads();

    // fm[i][j] = sum_c Wt[c][i]*T1[c][j] + T3[i]*bp[j] + bt[i]*(T2[j] + N*bp[j])
    for (int idx = tid; idx < F_*F_; idx += 256) {
        int i = idx >> 6, j = idx & 63;
        float s = 0.f;
        for (int c = 0; c < C_; ++c) s = fmaf(Wt[c*F_ + i], T1[c][j], s);
        s += T3[i]*bp[j] + bt[i]*(T2[j] + (float)N_ * bp[j]);
        fmb[i][j] = s;
    }
    __syncthreads();

    // softmax over j per row i
    if (tid < F_) {
        const int i = tid;
        float m = -3.0e38f;
        for (int j = 0; j < F_; ++j) m = fmaxf(m, fmb[i][j]);
        float sum = 0.f;
        for (int j = 0; j < F_; ++j) { float e = expf(fmb[i][j] - m); fmb[i][j] = e; sum += e; }
        float inv = 1.f / sum;
        float* up = U + (size_t)b * F_ * F_ + (size_t)i * F_;
        for (int j = 0; j < F_; ++j) up[j] = fmb[i][j] * inv;
    }
}

// Kernel C: per (b, half, w): P = G_w^T Wo ; Out = U^T P ; fused bias + BN
__global__ __launch_bounds__(256, 2)
void kC(const unsigned short* __restrict__ g, const float* __restrict__ U,
        const float* __restrict__ Wo, const float* __restrict__ bo,
        const float* __restrict__ gamma_, const float* __restrict__ beta_,
        const float* __restrict__ mmean, const float* __restrict__ mvar,
        float* __restrict__ out)
{
    __shared__ float Us[F_][F_];
    __shared__ float Wos[F_][F_];
    __shared__ float Gs[F_][F_];
    __shared__ float Ps[F_][F_];

    const int tid = threadIdx.x;
    const int wg   = blockIdx.x & 31;
    const int half = (blockIdx.x >> 5) & 1;
    const int b    = blockIdx.x >> 6;

    for (int t = tid; t < (F_*F_)/4; t += 256) {
        ((float4*)Us)[t]  = ((const float4*)(U + (size_t)b * F_ * F_))[t];
        ((float4*)Wos)[t] = ((const float4*)Wo)[t];
    }

    const int ti = tid >> 4;    // 0..15
    const int te = tid & 15;    // 0..15

    float scl[4], sft[4];
    {
        const int e0 = te * 4;
        for (int v = 0; v < 4; ++v) {
            float sc = gamma_[e0+v] * rsqrtf(mvar[e0+v] + EPSV);
            scl[v] = sc;
            sft[v] = (bo[e0+v] - mmean[e0+v]) * sc + beta_[e0+v];
        }
    }

    for (int wi = 0; wi < 4; ++wi) {
        const int w = wg * 4 + wi;
        const unsigned short* gsrc = g + ((size_t)b * N_ + (size_t)half * (N_/2) + (size_t)w * 64) * F_;
        __syncthreads();   // prior iter's Gs/Ps readers done
        for (int t = tid; t < 1024; t += 256) {
            ushort4 v = ((const ushort4*)gsrc)[t];
            int e  = t >> 4;
            int i0 = (t & 15) * 4;
            Gs[e][i0+0] = b2f(v.x);
            Gs[e][i0+1] = b2f(v.y);
            Gs[e][i0+2] = b2f(v.z);
            Gs[e][i0+3] = b2f(v.w);
        }
        __syncthreads();

        // P[i][e'] = sum_e Gs[e][i]*Wos[e][e']
        float pa[4][4];
        for (int u = 0; u < 4; ++u) for (int v = 0; v < 4; ++v) pa[u][v] = 0.f;
        #pragma unroll 4
        for (int e = 0; e < F_; ++e) {
            float4 av = *(const float4*)&Gs[e][ti*4];
            float4 bv = *(const float4*)&Wos[e][te*4];
            float a[4]  = {av.x, av.y, av.z, av.w};
            float bb[4] = {bv.x, bv.y, bv.z, bv.w};
            for (int u = 0; u < 4; ++u)
                for (int v = 0; v < 4; ++v)
                    pa[u][v] = fmaf(a[u], bb[v], pa[u][v]);
        }
        for (int u = 0; u < 4; ++u)
            *(float4*)&Ps[ti*4+u][te*4] = make_float4(pa[u][0], pa[u][1], pa[u][2], pa[u][3]);
        __syncthreads();

        // Out[j][e'] = sum_i Us[i][j]*Ps[i][e']
        float oa[4][4];
        for (int u = 0; u < 4; ++u) for (int v = 0; v < 4; ++v) oa[u][v] = 0.f;
        #pragma unroll 4
        for (int i = 0; i < F_; ++i) {
            float4 av = *(const float4*)&Us[i][ti*4];
            float4 bv = *(const float4*)&Ps[i][te*4];
            float a[4]  = {av.x, av.y, av.z, av.w};
            float bb[4] = {bv.x, bv.y, bv.z, bv.w};
            for (int u = 0; u < 4; ++u)
                for (int v = 0; v < 4; ++v)
                    oa[u][v] = fmaf(a[u], bb[v], oa[u][v]);
        }

        for (int u = 0; u < 4; ++u) {
            int j = ti*4 + u;
            int h = 2*j + half;
            float* op = out + (((size_t)b * H_ + h) * W_ + w) * F_ + te*4;
            float4 r;
            r.x = oa[u][0]*scl[0] + sft[0];
            r.y = oa[u][1]*scl[1] + sft[1];
            r.z = oa[u][2]*scl[2] + sft[2];
            r.w = oa[u][3]*scl[3] + sft[3];
            *(float4*)op = r;
        }
    }
}

extern "C" void kernel_launch(void* const* d_in, const int* in_sizes, int n_in,
                              void* d_out, int out_size, void* d_ws, size_t ws_size,
                              hipStream_t stream)
{
    const float* x  = (const float*)d_in[0];
    const float* Wg = (const float*)d_in[1];
    const float* bg = (const float*)d_in[2];
    const float* Wt = (const float*)d_in[3];
    const float* bt = (const float*)d_in[4];
    const float* Wp = (const float*)d_in[5];
    const float* bp = (const float*)d_in[6];
    const float* Wo = (const float*)d_in[7];
    const float* bo = (const float*)d_in[8];
    const float* ga = (const float*)d_in[9];
    const float* be = (const float*)d_in[10];
    const float* mm = (const float*)d_in[11];
    const float* mv = (const float*)d_in[12];
    float* out = (float*)d_out;

    // ws layout: g(bf16) 32 MiB | Spart 32 MiB | cspart 256 KiB | U 256 KiB  (~64.5 MiB)
    char* ws = (char*)d_ws;
    unsigned short* g = (unsigned short*)ws;
    size_t off = (size_t)B_ * N_ * F_ * sizeof(unsigned short);
    float* Spart = (float*)(ws + off);
    off += (size_t)B_ * SPLITS * C_ * C_ * sizeof(float);
    float* cspart = (float*)(ws + off);
    off += (size_t)B_ * SPLITS * C_ * sizeof(float);
    float* U = (float*)(ws + off);

    kA<<<B_ * SPLITS, 256, 0, stream>>>(x, Wg, bg, g, Spart, cspart);
    kB<<<B_, 256, 0, stream>>>(Spart, cspart, Wt, bt, Wp, bp, U);
    kC<<<B_ * 2 * (W_/4), 256, 0, stream>>>(g, U, Wo, bo, ga, be, mm, mv, out);
}

// Round 2
// 258.295 us; speedup vs baseline: 3.6141x; 3.6141x over previous
//
#include <hip/hip_runtime.h>
#include <stdint.h>

#define B_ 16
#define H_ 128
#define W_ 128
#define C_ 128
#define F_ 64
#define N_ (H_*W_)          // 16384
#define SPLITS 32
#define RPB (N_/SPLITS)     // 512 rows per block
#define CH 64               // rows per chunk in kS
#define EPSV 1e-3f

typedef __attribute__((ext_vector_type(8))) short bf16x8;
typedef __attribute__((ext_vector_type(16))) float f32x16;

__device__ __forceinline__ unsigned short f2b(float f) {
    unsigned int x = __float_as_uint(f);
    x += 0x7fffu + ((x >> 16) & 1u);
    return (unsigned short)(x >> 16);
}
__device__ __forceinline__ float b2f(unsigned short u) {
    return __uint_as_float(((unsigned int)u) << 16);
}

// ---------------------------------------------------------------------------
// Kernel S: fused fp32->split-bf16 conversion + S = X^T X partials (MFMA,
// hi*hi + hi*lo + lo*hi) + column sums + g = hi @ Wg + bg (MFMA, bf16 out).
// Grid: B_*SPLITS blocks x 256 threads (4 waves). Each block owns 512 rows.
// ---------------------------------------------------------------------------
__global__ __launch_bounds__(256, 2)
void kS(const float* __restrict__ x, const float* __restrict__ Wg,
        const float* __restrict__ bg, unsigned short* __restrict__ g,
        float* __restrict__ Spart, float* __restrict__ cspart)
{
    // channel-major staging: u32 word = bf16(row 2np) | bf16(row 2np+1)<<16
    // u16 row stride = 72 (16B-aligned rows, even bank spread for b128 reads)
    __shared__ unsigned int  xsT_hi[C_][36];     // 18.0 KiB
    __shared__ unsigned int  xsT_lo[C_][36];     // 18.0 KiB
    __shared__ unsigned short xs_hi[CH][136];    // row-major hi copy, 17.0 KiB
    __shared__ unsigned short WgT[F_][136];      // WgT[f][c] bf16, 17.0 KiB

    const int tid  = threadIdx.x;
    const int lane = tid & 63;
    const int w    = tid >> 6;          // wave 0..3
    const int b    = blockIdx.x >> 5;
    const int sp   = blockIdx.x & 31;

    // Build WgT (bf16) once per block
    for (int i = tid; i < C_*F_; i += 256) {
        int c = i >> 6, f = i & 63;
        WgT[f][c] = f2b(Wg[i]);
    }

    const float* xb = x + ((size_t)b * N_ + (size_t)sp * RPB) * C_;
    unsigned short* gb = g + ((size_t)b * N_ + (size_t)sp * RPB) * F_;

    const int rowA = lane & 31;
    const int kgrp = (lane >> 5) * 8;   // k sub-offset (u16 elems)
    const int c1b  = (w & 1) * 64;      // S quadrant rows
    const int c2b  = (w >> 1) * 64;     // S quadrant cols
    const int nbG  = (w & 1) * 32;      // g n-block within chunk
    const int fbG  = (w >> 1) * 32;     // g f-block

    const float bgl = bg[fbG + rowA];

    f32x16 accS[2][2];
    #pragma unroll
    for (int ti = 0; ti < 2; ++ti)
        #pragma unroll
        for (int tj = 0; tj < 2; ++tj)
            #pragma unroll
            for (int e = 0; e < 16; ++e) accS[ti][tj][e] = 0.f;
    float csum = 0.f;

    for (int ch = 0; ch < RPB/CH; ++ch) {
        __syncthreads();   // prior chunk's readers done before overwrite
        const float* xc = xb + (size_t)ch * CH * C_;
        #pragma unroll
        for (int p = 0; p < 4; ++p) {
            const int idx = tid + 256*p;
            const int np  = idx & 31;
            const int c4  = (idx >> 5) * 4;
            const float* r0 = xc + (size_t)(2*np) * C_ + c4;
            float4 a = *(const float4*)r0;
            float4 q = *(const float4*)(r0 + C_);
            unsigned short ha0 = f2b(a.x), ha1 = f2b(a.y), ha2 = f2b(a.z), ha3 = f2b(a.w);
            unsigned short hb0 = f2b(q.x), hb1 = f2b(q.y), hb2 = f2b(q.z), hb3 = f2b(q.w);
            unsigned short la0 = f2b(a.x - b2f(ha0)), la1 = f2b(a.y - b2f(ha1));
            unsigned short la2 = f2b(a.z - b2f(ha2)), la3 = f2b(a.w - b2f(ha3));
            unsigned short lb0 = f2b(q.x - b2f(hb0)), lb1 = f2b(q.y - b2f(hb1));
            unsigned short lb2 = f2b(q.z - b2f(hb2)), lb3 = f2b(q.w - b2f(hb3));
            xsT_hi[c4+0][np] = (unsigned)ha0 | ((unsigned)hb0 << 16);
            xsT_hi[c4+1][np] = (unsigned)ha1 | ((unsigned)hb1 << 16);
            xsT_hi[c4+2][np] = (unsigned)ha2 | ((unsigned)hb2 << 16);
            xsT_hi[c4+3][np] = (unsigned)ha3 | ((unsigned)hb3 << 16);
            xsT_lo[c4+0][np] = (unsigned)la0 | ((unsigned)lb0 << 16);
            xsT_lo[c4+1][np] = (unsigned)la1 | ((unsigned)lb1 << 16);
            xsT_lo[c4+2][np] = (unsigned)la2 | ((unsigned)lb2 << 16);
            xsT_lo[c4+3][np] = (unsigned)la3 | ((unsigned)lb3 << 16);
            ushort4 u0; u0.x = ha0; u0.y = ha1; u0.z = ha2; u0.w = ha3;
            ushort4 u1; u1.x = hb0; u1.y = hb1; u1.z = hb2; u1.w = hb3;
            *(ushort4*)&xs_hi[2*np  ][c4] = u0;
            *(ushort4*)&xs_hi[2*np+1][c4] = u1;
        }
        __syncthreads();

        // column sums (hi+lo ~ exact) — threads 0..127, one channel each
        if (tid < C_) {
            #pragma unroll 8
            for (int np = 0; np < 32; ++np) {
                unsigned int h = xsT_hi[tid][np];
                unsigned int l = xsT_lo[tid][np];
                csum += b2f((unsigned short)(h & 0xffffu)) + b2f((unsigned short)(h >> 16))
                      + b2f((unsigned short)(l & 0xffffu)) + b2f((unsigned short)(l >> 16));
            }
        }

        // S phase: 2x2 tiles of 32x32, K = 64 rows in steps of 16
        #pragma unroll
        for (int ks = 0; ks < 4; ++ks) {
            const int kn = ks*16 + kgrp;
            bf16x8 Ah[2], Al[2], Bh[2], Bl[2];
            #pragma unroll
            for (int t = 0; t < 2; ++t) {
                const unsigned short* rAh = (const unsigned short*)&xsT_hi[c1b + 32*t + rowA][0];
                const unsigned short* rAl = (const unsigned short*)&xsT_lo[c1b + 32*t + rowA][0];
                Ah[t] = *(const bf16x8*)(rAh + kn);
                Al[t] = *(const bf16x8*)(rAl + kn);
                const unsigned short* rBh = (const unsigned short*)&xsT_hi[c2b + 32*t + rowA][0];
                const unsigned short* rBl = (const unsigned short*)&xsT_lo[c2b + 32*t + rowA][0];
                Bh[t] = *(const bf16x8*)(rBh + kn);
                Bl[t] = *(const bf16x8*)(rBl + kn);
            }
            #pragma unroll
            for (int ti = 0; ti < 2; ++ti)
                #pragma unroll
                for (int tj = 0; tj < 2; ++tj) {
                    accS[ti][tj] = __builtin_amdgcn_mfma_f32_32x32x16_bf16(Ah[ti], Bh[tj], accS[ti][tj], 0, 0, 0);
                    accS[ti][tj] = __builtin_amdgcn_mfma_f32_32x32x16_bf16(Ah[ti], Bl[tj], accS[ti][tj], 0, 0, 0);
                    accS[ti][tj] = __builtin_amdgcn_mfma_f32_32x32x16_bf16(Al[ti], Bh[tj], accS[ti][tj], 0, 0, 0);
                }
        }

        // g phase: one 32x32 tile per wave, K = C_ in steps of 16
        {
            f32x16 aG;
            #pragma unroll
            for (int e = 0; e < 16; ++e) aG[e] = 0.f;
            #pragma unroll
            for (int ks = 0; ks < 8; ++ks) {
                bf16x8 av = *(const bf16x8*)&xs_hi[nbG + rowA][ks*16 + kgrp];
                bf16x8 wv = *(const bf16x8*)&WgT [fbG + rowA][ks*16 + kgrp];
                aG = __builtin_amdgcn_mfma_f32_32x32x16_bf16(av, wv, aG, 0, 0, 0);
            }
            const int fcol = fbG + (lane & 31);
            #pragma unroll
            for (int r = 0; r < 16; ++r) {
                int nloc = (r & 3) + 8*(r >> 2) + 4*(lane >> 5);
                int n = ch*CH + nbG + nloc;
                gb[(size_t)n * F_ + fcol] = f2b(aG[r] + bgl);
            }
        }
    }

    // write S partials (each wave owns one 64x64 quadrant)
    float* so = Spart + (size_t)(b * SPLITS + sp) * (size_t)(C_ * C_);
    #pragma unroll
    for (int ti = 0; ti < 2; ++ti)
        #pragma unroll
        for (int tj = 0; tj < 2; ++tj)
            #pragma unroll
            for (int r = 0; r < 16; ++r) {
                int c1 = c1b + 32*ti + (r & 3) + 8*(r >> 2) + 4*(lane >> 5);
                int c2 = c2b + 32*tj + (lane & 31);
                so[(size_t)c1 * C_ + c2] = accS[ti][tj][r];
            }
    if (tid < C_)
        cspart[(size_t)(b * SPLITS + sp) * C_ + tid] = csum;
}

// Kernel B: reduce partials; fm = Wt^T S Wp + bias terms; softmax rows -> U
__global__ __launch_bounds__(256, 1)
void kB(const float* __restrict__ Spart, const float* __restrict__ cspart,
        const float* __restrict__ Wt, const float* __restrict__ bt,
        const float* __restrict__ Wp, const float* __restrict__ bp,
        float* __restrict__ U)
{
    __shared__ float S[C_][C_];
    __shared__ float T1[C_][F_];
    __shared__ float fmb[F_][F_];
    __shared__ float cs[C_];
    __shared__ float T2[F_];
    __shared__ float T3[F_];

    const int tid = threadIdx.x;
    const int b = blockIdx.x;

    const float* sp0 = Spart + (size_t)b * SPLITS * C_ * C_;
    for (int idx = tid; idx < C_*C_; idx += 256) {
        float s = 0.f;
        for (int k = 0; k < SPLITS; ++k) s += sp0[(size_t)k * C_ * C_ + idx];
        ((float*)S)[idx] = s;
    }
    if (tid < C_) {
        const float* cp0 = cspart + (size_t)b * SPLITS * C_ + tid;
        float s = 0.f;
        for (int k = 0; k < SPLITS; ++k) s += cp0[(size_t)k * C_];
        cs[tid] = s;
    }
    __syncthreads();

    for (int idx = tid; idx < C_*F_; idx += 256) {
        int c = idx >> 6, j = idx & 63;
        float s = 0.f;
        for (int k = 0; k < C_; ++k) s = fmaf(S[c][k], Wp[k*F_ + j], s);
        T1[c][j] = s;
    }
    if (tid < F_) {
        float s = 0.f;
        for (int k = 0; k < C_; ++k) s = fmaf(cs[k], Wp[k*F_ + tid], s);
        T2[tid] = s;
    } else if (tid < 2*F_) {
        int i = tid - F_;
        float s = 0.f;
        for (int k = 0; k < C_; ++k) s = fmaf(cs[k], Wt[k*F_ + i], s);
        T3[i] = s;
    }
    __syncthreads();

    for (int idx = tid; idx < F_*F_; idx += 256) {
        int i = idx >> 6, j = idx & 63;
        float s = 0.f;
        for (int c = 0; c < C_; ++c) s = fmaf(Wt[c*F_ + i], T1[c][j], s);
        s += T3[i]*bp[j] + bt[i]*(T2[j] + (float)N_ * bp[j]);
        fmb[i][j] = s;
    }
    __syncthreads();

    if (tid < F_) {
        const int i = tid;
        float m = -3.0e38f;
        for (int j = 0; j < F_; ++j) m = fmaxf(m, fmb[i][j]);
        float sum = 0.f;
        for (int j = 0; j < F_; ++j) { float e = expf(fmb[i][j] - m); fmb[i][j] = e; sum += e; }
        float inv = 1.f / sum;
        float* up = U + (size_t)b * F_ * F_ + (size_t)i * F_;
        for (int j = 0; j < F_; ++j) up[j] = fmb[i][j] * inv;
    }
}

// Kernel C: per (b, half, w): P = G_w^T Wo ; Out = U^T P ; fused bias + BN
__global__ __launch_bounds__(256, 2)
void kC(const unsigned short* __restrict__ g, const float* __restrict__ U,
        const float* __restrict__ Wo, const float* __restrict__ bo,
        const float* __restrict__ gamma_, const float* __restrict__ beta_,
        const float* __restrict__ mmean, const float* __restrict__ mvar,
        float* __restrict__ out)
{
    __shared__ float Us[F_][F_];
    __shared__ float Wos[F_][F_];
    __shared__ float Gs[F_][F_];
    __shared__ float Ps[F_][F_];

    const int tid = threadIdx.x;
    const int wg   = blockIdx.x & 31;
    const int half = (blockIdx.x >> 5) & 1;
    const int b    = blockIdx.x >> 6;

    for (int t = tid; t < (F_*F_)/4; t += 256) {
        ((float4*)Us)[t]  = ((const float4*)(U + (size_t)b * F_ * F_))[t];
        ((float4*)Wos)[t] = ((const float4*)Wo)[t];
    }

    const int ti = tid >> 4;
    const int te = tid & 15;

    float scl[4], sft[4];
    {
        const int e0 = te * 4;
        for (int v = 0; v < 4; ++v) {
            float sc = gamma_[e0+v] * rsqrtf(mvar[e0+v] + EPSV);
            scl[v] = sc;
            sft[v] = (bo[e0+v] - mmean[e0+v]) * sc + beta_[e0+v];
        }
    }

    for (int wi = 0; wi < 4; ++wi) {
        const int w = wg * 4 + wi;
        const unsigned short* gsrc = g + ((size_t)b * N_ + (size_t)half * (N_/2) + (size_t)w * 64) * F_;
        __syncthreads();
        for (int t = tid; t < 1024; t += 256) {
            ushort4 v = ((const ushort4*)gsrc)[t];
            int e  = t >> 4;
            int i0 = (t & 15) * 4;
            Gs[e][i0+0] = b2f(v.x);
            Gs[e][i0+1] = b2f(v.y);
            Gs[e][i0+2] = b2f(v.z);
            Gs[e][i0+3] = b2f(v.w);
        }
        __syncthreads();

        float pa[4][4];
        for (int u = 0; u < 4; ++u) for (int v = 0; v < 4; ++v) pa[u][v] = 0.f;
        #pragma unroll 4
        for (int e = 0; e < F_; ++e) {
            float4 av = *(const float4*)&Gs[e][ti*4];
            float4 bv = *(const float4*)&Wos[e][te*4];
            float a[4]  = {av.x, av.y, av.z, av.w};
            float bb[4] = {bv.x, bv.y, bv.z, bv.w};
            for (int u = 0; u < 4; ++u)
                for (int v = 0; v < 4; ++v)
                    pa[u][v] = fmaf(a[u], bb[v], pa[u][v]);
        }
        for (int u = 0; u < 4; ++u)
            *(float4*)&Ps[ti*4+u][te*4] = make_float4(pa[u][0], pa[u][1], pa[u][2], pa[u][3]);
        __syncthreads();

        float oa[4][4];
        for (int u = 0; u < 4; ++u) for (int v = 0; v < 4; ++v) oa[u][v] = 0.f;
        #pragma unroll 4
        for (int i = 0; i < F_; ++i) {
            float4 av = *(const float4*)&Us[i][ti*4];
            float4 bv = *(const float4*)&Ps[i][te*4];
            float a[4]  = {av.x, av.y, av.z, av.w};
            float bb[4] = {bv.x, bv.y, bv.z, bv.w};
            for (int u = 0; u < 4; ++u)
                for (int v = 0; v < 4; ++v)
                    oa[u][v] = fmaf(a[u], bb[v], oa[u][v]);
        }

        for (int u = 0; u < 4; ++u) {
            int j = ti*4 + u;
            int h = 2*j + half;
            float* op = out + (((size_t)b * H_ + h) * W_ + w) * F_ + te*4;
            float4 r;
            r.x = oa[u][0]*scl[0] + sft[0];
            r.y = oa[u][1]*scl[1] + sft[1];
            r.z = oa[u][2]*scl[2] + sft[2];
            r.w = oa[u][3]*scl[3] + sft[3];
            *(float4*)op = r;
        }
    }
}

extern "C" void kernel_launch(void* const* d_in, const int* in_sizes, int n_in,
                              void* d_out, int out_size, void* d_ws, size_t ws_size,
                              hipStream_t stream)
{
    const float* x  = (const float*)d_in[0];
    const float* Wg = (const float*)d_in[1];
    const float* bg = (const float*)d_in[2];
    const float* Wt = (const float*)d_in[3];
    const float* bt = (const float*)d_in[4];
    const float* Wp = (const float*)d_in[5];
    const float* bp = (const float*)d_in[6];
    const float* Wo = (const float*)d_in[7];
    const float* bo = (const float*)d_in[8];
    const float* ga = (const float*)d_in[9];
    const float* be = (const float*)d_in[10];
    const float* mm = (const float*)d_in[11];
    const float* mv = (const float*)d_in[12];
    float* out = (float*)d_out;

    char* ws = (char*)d_ws;
    unsigned short* g = (unsigned short*)ws;
    size_t off = (size_t)B_ * N_ * F_ * sizeof(unsigned short);
    float* Spart = (float*)(ws + off);
    off += (size_t)B_ * SPLITS * C_ * C_ * sizeof(float);
    float* cspart = (float*)(ws + off);
    off += (size_t)B_ * SPLITS * C_ * sizeof(float);
    float* U = (float*)(ws + off);

    kS<<<B_ * SPLITS, 256, 0, stream>>>(x, Wg, bg, g, Spart, cspart);
    kB<<<B_, 256, 0, stream>>>(Spart, cspart, Wt, bt, Wp, bp, U);
    kC<<<B_ * 2 * (W_/4), 256, 0, stream>>>(g, U, Wo, bo, ga, be, mm, mv, out);
}

// Round 3
// 152.252 us; speedup vs baseline: 6.1312x; 1.6965x over previous
//
#include <hip/hip_runtime.h>
#include <stdint.h>

#define B_ 16
#define H_ 128
#define W_ 128
#define C_ 128
#define F_ 64
#define N_ (H_*W_)          // 16384
#define SPLITS 32
#define RPB (N_/SPLITS)     // 512 rows per block
#define CH 64               // rows per chunk in kS
#define EPSV 1e-3f

typedef __attribute__((ext_vector_type(8))) short bf16x8;
typedef __attribute__((ext_vector_type(16))) float f32x16;

__device__ __forceinline__ unsigned short f2b(float f) {
    unsigned int x = __float_as_uint(f);
    x += 0x7fffu + ((x >> 16) & 1u);
    return (unsigned short)(x >> 16);
}
__device__ __forceinline__ float b2f(unsigned short u) {
    return __uint_as_float(((unsigned int)u) << 16);
}

// ---------------------------------------------------------------------------
// Kernel S: fused fp32->split-bf16 conversion + S = X^T X partials (MFMA,
// hi*hi + hi*lo + lo*hi) + column sums + g = hi @ Wg + bg (MFMA, bf16 out).
// ---------------------------------------------------------------------------
__global__ __launch_bounds__(256, 2)
void kS(const float* __restrict__ x, const float* __restrict__ Wg,
        const float* __restrict__ bg, unsigned short* __restrict__ g,
        float* __restrict__ Spart, float* __restrict__ cspart)
{
    __shared__ unsigned int  xsT_hi[C_][36];
    __shared__ unsigned int  xsT_lo[C_][36];
    __shared__ unsigned short xs_hi[CH][136];
    __shared__ unsigned short WgT[F_][136];

    const int tid  = threadIdx.x;
    const int lane = tid & 63;
    const int w    = tid >> 6;
    const int b    = blockIdx.x >> 5;
    const int sp   = blockIdx.x & 31;

    for (int i = tid; i < C_*F_; i += 256) {
        int c = i >> 6, f = i & 63;
        WgT[f][c] = f2b(Wg[i]);
    }

    const float* xb = x + ((size_t)b * N_ + (size_t)sp * RPB) * C_;
    unsigned short* gb = g + ((size_t)b * N_ + (size_t)sp * RPB) * F_;

    const int rowA = lane & 31;
    const int kgrp = (lane >> 5) * 8;
    const int c1b  = (w & 1) * 64;
    const int c2b  = (w >> 1) * 64;
    const int nbG  = (w & 1) * 32;
    const int fbG  = (w >> 1) * 32;

    const float bgl = bg[fbG + rowA];

    f32x16 accS[2][2];
    #pragma unroll
    for (int ti = 0; ti < 2; ++ti)
        #pragma unroll
        for (int tj = 0; tj < 2; ++tj)
            #pragma unroll
            for (int e = 0; e < 16; ++e) accS[ti][tj][e] = 0.f;
    float csum = 0.f;

    for (int ch = 0; ch < RPB/CH; ++ch) {
        __syncthreads();
        const float* xc = xb + (size_t)ch * CH * C_;
        #pragma unroll
        for (int p = 0; p < 4; ++p) {
            const int idx = tid + 256*p;
            const int np  = idx & 31;
            const int c4  = (idx >> 5) * 4;
            const float* r0 = xc + (size_t)(2*np) * C_ + c4;
            float4 a = *(const float4*)r0;
            float4 q = *(const float4*)(r0 + C_);
            unsigned short ha0 = f2b(a.x), ha1 = f2b(a.y), ha2 = f2b(a.z), ha3 = f2b(a.w);
            unsigned short hb0 = f2b(q.x), hb1 = f2b(q.y), hb2 = f2b(q.z), hb3 = f2b(q.w);
            unsigned short la0 = f2b(a.x - b2f(ha0)), la1 = f2b(a.y - b2f(ha1));
            unsigned short la2 = f2b(a.z - b2f(ha2)), la3 = f2b(a.w - b2f(ha3));
            unsigned short lb0 = f2b(q.x - b2f(hb0)), lb1 = f2b(q.y - b2f(hb1));
            unsigned short lb2 = f2b(q.z - b2f(hb2)), lb3 = f2b(q.w - b2f(hb3));
            xsT_hi[c4+0][np] = (unsigned)ha0 | ((unsigned)hb0 << 16);
            xsT_hi[c4+1][np] = (unsigned)ha1 | ((unsigned)hb1 << 16);
            xsT_hi[c4+2][np] = (unsigned)ha2 | ((unsigned)hb2 << 16);
            xsT_hi[c4+3][np] = (unsigned)ha3 | ((unsigned)hb3 << 16);
            xsT_lo[c4+0][np] = (unsigned)la0 | ((unsigned)lb0 << 16);
            xsT_lo[c4+1][np] = (unsigned)la1 | ((unsigned)lb1 << 16);
            xsT_lo[c4+2][np] = (unsigned)la2 | ((unsigned)lb2 << 16);
            xsT_lo[c4+3][np] = (unsigned)la3 | ((unsigned)lb3 << 16);
            ushort4 u0; u0.x = ha0; u0.y = ha1; u0.z = ha2; u0.w = ha3;
            ushort4 u1; u1.x = hb0; u1.y = hb1; u1.z = hb2; u1.w = hb3;
            *(ushort4*)&xs_hi[2*np  ][c4] = u0;
            *(ushort4*)&xs_hi[2*np+1][c4] = u1;
        }
        __syncthreads();

        if (tid < C_) {
            #pragma unroll 8
            for (int np = 0; np < 32; ++np) {
                unsigned int h = xsT_hi[tid][np];
                unsigned int l = xsT_lo[tid][np];
                csum += b2f((unsigned short)(h & 0xffffu)) + b2f((unsigned short)(h >> 16))
                      + b2f((unsigned short)(l & 0xffffu)) + b2f((unsigned short)(l >> 16));
            }
        }

        #pragma unroll
        for (int ks = 0; ks < 4; ++ks) {
            const int kn = ks*16 + kgrp;
            bf16x8 Ah[2], Al[2], Bh[2], Bl[2];
            #pragma unroll
            for (int t = 0; t < 2; ++t) {
                const unsigned short* rAh = (const unsigned short*)&xsT_hi[c1b + 32*t + rowA][0];
                const unsigned short* rAl = (const unsigned short*)&xsT_lo[c1b + 32*t + rowA][0];
                Ah[t] = *(const bf16x8*)(rAh + kn);
                Al[t] = *(const bf16x8*)(rAl + kn);
                const unsigned short* rBh = (const unsigned short*)&xsT_hi[c2b + 32*t + rowA][0];
                const unsigned short* rBl = (const unsigned short*)&xsT_lo[c2b + 32*t + rowA][0];
                Bh[t] = *(const bf16x8*)(rBh + kn);
                Bl[t] = *(const bf16x8*)(rBl + kn);
            }
            #pragma unroll
            for (int ti = 0; ti < 2; ++ti)
                #pragma unroll
                for (int tj = 0; tj < 2; ++tj) {
                    accS[ti][tj] = __builtin_amdgcn_mfma_f32_32x32x16_bf16(Ah[ti], Bh[tj], accS[ti][tj], 0, 0, 0);
                    accS[ti][tj] = __builtin_amdgcn_mfma_f32_32x32x16_bf16(Ah[ti], Bl[tj], accS[ti][tj], 0, 0, 0);
                    accS[ti][tj] = __builtin_amdgcn_mfma_f32_32x32x16_bf16(Al[ti], Bh[tj], accS[ti][tj], 0, 0, 0);
                }
        }

        {
            f32x16 aG;
            #pragma unroll
            for (int e = 0; e < 16; ++e) aG[e] = 0.f;
            #pragma unroll
            for (int ks = 0; ks < 8; ++ks) {
                bf16x8 av = *(const bf16x8*)&xs_hi[nbG + rowA][ks*16 + kgrp];
                bf16x8 wv = *(const bf16x8*)&WgT [fbG + rowA][ks*16 + kgrp];
                aG = __builtin_amdgcn_mfma_f32_32x32x16_bf16(av, wv, aG, 0, 0, 0);
            }
            const int fcol = fbG + (lane & 31);
            #pragma unroll
            for (int r = 0; r < 16; ++r) {
                int nloc = (r & 3) + 8*(r >> 2) + 4*(lane >> 5);
                int n = ch*CH + nbG + nloc;
                gb[(size_t)n * F_ + fcol] = f2b(aG[r] + bgl);
            }
        }
    }

    float* so = Spart + (size_t)(b * SPLITS + sp) * (size_t)(C_ * C_);
    #pragma unroll
    for (int ti = 0; ti < 2; ++ti)
        #pragma unroll
        for (int tj = 0; tj < 2; ++tj)
            #pragma unroll
            for (int r = 0; r < 16; ++r) {
                int c1 = c1b + 32*ti + (r & 3) + 8*(r >> 2) + 4*(lane >> 5);
                int c2 = c2b + 32*tj + (lane & 31);
                so[(size_t)c1 * C_ + c2] = accS[ti][tj][r];
            }
    if (tid < C_)
        cspart[(size_t)(b * SPLITS + sp) * C_ + tid] = csum;
}

// ---------------------------------------------------------------------------
// Kernel R: reduce Spart over splits -> Sred ; cspart -> csred. Pure BW.
// Grid: B_*16 blocks x 256 threads.
// ---------------------------------------------------------------------------
__global__ __launch_bounds__(256, 8)
void kR(const float* __restrict__ Spart, const float* __restrict__ cspart,
        float* __restrict__ Sred, float* __restrict__ csred)
{
    const int b = blockIdx.x >> 4;
    const int r = blockIdx.x & 15;
    const int f4 = r*256 + threadIdx.x;          // float4 index 0..4095
    const float4* base = (const float4*)(Spart + (size_t)b * SPLITS * C_ * C_);
    float sx=0.f, sy=0.f, sz=0.f, sw=0.f;
    #pragma unroll 4
    for (int sp = 0; sp < SPLITS; ++sp) {
        float4 v = base[(size_t)sp * (C_*C_/4) + f4];
        sx += v.x; sy += v.y; sz += v.z; sw += v.w;
    }
    ((float4*)(Sred + (size_t)b * C_ * C_))[f4] = make_float4(sx, sy, sz, sw);

    if (r == 0 && threadIdx.x < C_) {
        float c = 0.f;
        #pragma unroll 4
        for (int sp = 0; sp < SPLITS; ++sp)
            c += cspart[((size_t)b * SPLITS + sp) * C_ + threadIdx.x];
        csred[(size_t)b * C_ + threadIdx.x] = c;
    }
}

// ---------------------------------------------------------------------------
// Kernel T: T1 = S @ Wp (per-batch 128x64, K=128), LDS-staged; also T2 = cs@Wp.
// Grid: B_*4 blocks x 256 threads. Block (b,q) computes T1 rows [32q,32q+32).
// ---------------------------------------------------------------------------
__global__ __launch_bounds__(256, 2)
void kT(const float* __restrict__ Sred, const float* __restrict__ csred,
        const float* __restrict__ Wp, float* __restrict__ T1buf,
        float* __restrict__ T2buf)
{
    __shared__ float Ss[32][C_];      // 16 KiB
    __shared__ float Wps[C_][F_];     // 32 KiB

    const int tid = threadIdx.x;
    const int b = blockIdx.x >> 2;
    const int q = blockIdx.x & 3;

    const float4* sg = (const float4*)(Sred + ((size_t)b * C_ + q*32) * C_);
    for (int t = tid; t < 32*C_/4; t += 256) ((float4*)Ss)[t] = sg[t];
    const float4* wg = (const float4*)Wp;
    for (int t = tid; t < C_*F_/4; t += 256) ((float4*)Wps)[t] = wg[t];
    __syncthreads();

    const int lane = tid & 63;
    const int w    = tid >> 6;

    float acc[8] = {0.f,0.f,0.f,0.f,0.f,0.f,0.f,0.f};
    #pragma unroll 2
    for (int k = 0; k < C_; k += 4) {
        float w0 = Wps[k+0][lane];
        float w1 = Wps[k+1][lane];
        float w2 = Wps[k+2][lane];
        float w3 = Wps[k+3][lane];
        #pragma unroll
        for (int cl = 0; cl < 8; ++cl) {
            float4 sv = *(const float4*)&Ss[w*8 + cl][k];
            float t = acc[cl];
            t = fmaf(sv.x, w0, t);
            t = fmaf(sv.y, w1, t);
            t = fmaf(sv.z, w2, t);
            t = fmaf(sv.w, w3, t);
            acc[cl] = t;
        }
    }
    #pragma unroll
    for (int cl = 0; cl < 8; ++cl) {
        int c = q*32 + w*8 + cl;
        T1buf[((size_t)b * C_ + c) * F_ + lane] = acc[cl];
    }

    // T2[j] = sum_c cs[c] * Wp[c][j]   (block q==0 only)
    if (q == 0 && tid < F_) {
        const float* cv = csred + (size_t)b * C_;
        float s = 0.f;
        for (int k = 0; k < C_; ++k) s = fmaf(cv[k], Wps[k][tid], s);
        T2buf[(size_t)b * F_ + tid] = s;
    }
}

// ---------------------------------------------------------------------------
// Kernel F: fm = Wt^T T1 + bias terms; in-register row softmax -> U.
// Grid: B_ blocks x 256 threads (4 waves x 16 rows, row across 64 lanes).
// ---------------------------------------------------------------------------
__global__ __launch_bounds__(256, 2)
void kF(const float* __restrict__ T1buf, const float* __restrict__ T2buf,
        const float* __restrict__ csred, const float* __restrict__ Wt,
        const float* __restrict__ bt, const float* __restrict__ bp,
        float* __restrict__ U)
{
    __shared__ float T1s[C_][F_];   // 32 KiB
    __shared__ float Wts[C_][F_];   // 32 KiB
    __shared__ float csb[C_];
    __shared__ float T2s[F_], T3s[F_], bts[F_], bps[F_];

    const int tid = threadIdx.x;
    const int b = blockIdx.x;

    for (int t = tid; t < C_*F_/4; t += 256) {
        ((float4*)T1s)[t] = ((const float4*)(T1buf + (size_t)b * C_ * F_))[t];
        ((float4*)Wts)[t] = ((const float4*)Wt)[t];
    }
    if (tid < C_) csb[tid] = csred[(size_t)b * C_ + tid];
    if (tid < F_) {
        T2s[tid] = T2buf[(size_t)b * F_ + tid];
        bts[tid] = bt[tid];
        bps[tid] = bp[tid];
    }
    __syncthreads();

    if (tid < F_) {
        float s = 0.f;
        for (int c = 0; c < C_; ++c) s = fmaf(csb[c], Wts[c][tid], s);
        T3s[tid] = s;
    }
    __syncthreads();

    const int lane = tid & 63;   // j
    const int w    = tid >> 6;   // wave -> rows i = 16w..16w+15

    float acc[16];
    #pragma unroll
    for (int r = 0; r < 16; ++r) acc[r] = 0.f;

    #pragma unroll 2
    for (int c = 0; c < C_; ++c) {
        float t1 = T1s[c][lane];
        #pragma unroll
        for (int u = 0; u < 4; ++u) {
            float4 wv = *(const float4*)&Wts[c][w*16 + u*4];
            acc[u*4+0] = fmaf(wv.x, t1, acc[u*4+0]);
            acc[u*4+1] = fmaf(wv.y, t1, acc[u*4+1]);
            acc[u*4+2] = fmaf(wv.z, t1, acc[u*4+2]);
            acc[u*4+3] = fmaf(wv.w, t1, acc[u*4+3]);
        }
    }

    const float bpj = bps[lane];
    const float t2j = T2s[lane];
    #pragma unroll
    for (int r = 0; r < 16; ++r) {
        const int i = w*16 + r;
        float v = acc[r] + T3s[i]*bpj + bts[i]*(t2j + (float)N_ * bpj);
        float m = v;
        #pragma unroll
        for (int o = 32; o; o >>= 1) m = fmaxf(m, __shfl_xor(m, o));
        float e = expf(v - m);
        float s = e;
        #pragma unroll
        for (int o = 32; o; o >>= 1) s += __shfl_xor(s, o);
        U[((size_t)b * F_ + i) * F_ + lane] = e / s;
    }
}

// ---------------------------------------------------------------------------
// Kernel C: per (b, half, w): P = G_w^T Wo ; Out = U^T P ; fused bias + BN
// ---------------------------------------------------------------------------
__global__ __launch_bounds__(256, 2)
void kC(const unsigned short* __restrict__ g, const float* __restrict__ U,
        const float* __restrict__ Wo, const float* __restrict__ bo,
        const float* __restrict__ gamma_, const float* __restrict__ beta_,
        const float* __restrict__ mmean, const float* __restrict__ mvar,
        float* __restrict__ out)
{
    __shared__ float Us[F_][F_];
    __shared__ float Wos[F_][F_];
    __shared__ float Gs[F_][F_];
    __shared__ float Ps[F_][F_];

    const int tid = threadIdx.x;
    const int wg   = blockIdx.x & 31;
    const int half = (blockIdx.x >> 5) & 1;
    const int b    = blockIdx.x >> 6;

    for (int t = tid; t < (F_*F_)/4; t += 256) {
        ((float4*)Us)[t]  = ((const float4*)(U + (size_t)b * F_ * F_))[t];
        ((float4*)Wos)[t] = ((const float4*)Wo)[t];
    }

    const int ti = tid >> 4;
    const int te = tid & 15;

    float scl[4], sft[4];
    {
        const int e0 = te * 4;
        for (int v = 0; v < 4; ++v) {
            float sc = gamma_[e0+v] * rsqrtf(mvar[e0+v] + EPSV);
            scl[v] = sc;
            sft[v] = (bo[e0+v] - mmean[e0+v]) * sc + beta_[e0+v];
        }
    }

    for (int wi = 0; wi < 4; ++wi) {
        const int w = wg * 4 + wi;
        const unsigned short* gsrc = g + ((size_t)b * N_ + (size_t)half * (N_/2) + (size_t)w * 64) * F_;
        __syncthreads();
        for (int t = tid; t < 1024; t += 256) {
            ushort4 v = ((const ushort4*)gsrc)[t];
            int e  = t >> 4;
            int i0 = (t & 15) * 4;
            Gs[e][i0+0] = b2f(v.x);
            Gs[e][i0+1] = b2f(v.y);
            Gs[e][i0+2] = b2f(v.z);
            Gs[e][i0+3] = b2f(v.w);
        }
        __syncthreads();

        float pa[4][4];
        for (int u = 0; u < 4; ++u) for (int v = 0; v < 4; ++v) pa[u][v] = 0.f;
        #pragma unroll 4
        for (int e = 0; e < F_; ++e) {
            float4 av = *(const float4*)&Gs[e][ti*4];
            float4 bv = *(const float4*)&Wos[e][te*4];
            float a[4]  = {av.x, av.y, av.z, av.w};
            float bb[4] = {bv.x, bv.y, bv.z, bv.w};
            for (int u = 0; u < 4; ++u)
                for (int v = 0; v < 4; ++v)
                    pa[u][v] = fmaf(a[u], bb[v], pa[u][v]);
        }
        for (int u = 0; u < 4; ++u)
            *(float4*)&Ps[ti*4+u][te*4] = make_float4(pa[u][0], pa[u][1], pa[u][2], pa[u][3]);
        __syncthreads();

        float oa[4][4];
        for (int u = 0; u < 4; ++u) for (int v = 0; v < 4; ++v) oa[u][v] = 0.f;
        #pragma unroll 4
        for (int i = 0; i < F_; ++i) {
            float4 av = *(const float4*)&Us[i][ti*4];
            float4 bv = *(const float4*)&Ps[i][te*4];
            float a[4]  = {av.x, av.y, av.z, av.w};
            float bb[4] = {bv.x, bv.y, bv.z, bv.w};
            for (int u = 0; u < 4; ++u)
                for (int v = 0; v < 4; ++v)
                    oa[u][v] = fmaf(a[u], bb[v], oa[u][v]);
        }

        for (int u = 0; u < 4; ++u) {
            int j = ti*4 + u;
            int h = 2*j + half;
            float* op = out + (((size_t)b * H_ + h) * W_ + w) * F_ + te*4;
            float4 r;
            r.x = oa[u][0]*scl[0] + sft[0];
            r.y = oa[u][1]*scl[1] + sft[1];
            r.z = oa[u][2]*scl[2] + sft[2];
            r.w = oa[u][3]*scl[3] + sft[3];
            *(float4*)op = r;
        }
    }
}

extern "C" void kernel_launch(void* const* d_in, const int* in_sizes, int n_in,
                              void* d_out, int out_size, void* d_ws, size_t ws_size,
                              hipStream_t stream)
{
    const float* x  = (const float*)d_in[0];
    const float* Wg = (const float*)d_in[1];
    const float* bg = (const float*)d_in[2];
    const float* Wt = (const float*)d_in[3];
    const float* bt = (const float*)d_in[4];
    const float* Wp = (const float*)d_in[5];
    const float* bp = (const float*)d_in[6];
    const float* Wo = (const float*)d_in[7];
    const float* bo = (const float*)d_in[8];
    const float* ga = (const float*)d_in[9];
    const float* be = (const float*)d_in[10];
    const float* mm = (const float*)d_in[11];
    const float* mv = (const float*)d_in[12];
    float* out = (float*)d_out;

    // ws layout: g 32MiB | Spart 32MiB (T1buf overlays its head after kR) |
    //            cspart 256KiB | U 256KiB | Sred 1MiB | csred 8KiB | T2buf 4KiB
    char* ws = (char*)d_ws;
    unsigned short* g = (unsigned short*)ws;
    size_t off = (size_t)B_ * N_ * F_ * sizeof(unsigned short);
    float* Spart = (float*)(ws + off);
    float* T1buf = (float*)(ws + off);   // overlay: Spart dead after kR
    off += (size_t)B_ * SPLITS * C_ * C_ * sizeof(float);
    float* cspart = (float*)(ws + off);
    off += (size_t)B_ * SPLITS * C_ * sizeof(float);
    float* U = (float*)(ws + off);
    off += (size_t)B_ * F_ * F_ * sizeof(float);
    float* Sred = (float*)(ws + off);
    off += (size_t)B_ * C_ * C_ * sizeof(float);
    float* csred = (float*)(ws + off);
    off += (size_t)B_ * C_ * sizeof(float);
    float* T2buf = (float*)(ws + off);

    kS<<<B_ * SPLITS, 256, 0, stream>>>(x, Wg, bg, g, Spart, cspart);
    kR<<<B_ * 16, 256, 0, stream>>>(Spart, cspart, Sred, csred);
    kT<<<B_ * 4, 256, 0, stream>>>(Sred, csred, Wp, T1buf, T2buf);
    kF<<<B_, 256, 0, stream>>>(T1buf, T2buf, csred, Wt, bt, bp, U);
    kC<<<B_ * 2 * (W_/4), 256, 0, stream>>>(g, U, Wo, bo, ga, be, mm, mv, out);
}

// Round 6
// 110.472 us; speedup vs baseline: 8.4500x; 1.3782x over previous
//
#include <hip/hip_runtime.h>
#include <stdint.h>

#define B_ 16
#define H_ 128
#define W_ 128
#define C_ 128
#define F_ 64
#define N_ (H_*W_)          // 16384
#define SPLITS 32
#define RPB (N_/SPLITS)     // 512 rows per block
#define CH 64               // rows per chunk in kS
#define EPSV 1e-3f

typedef __attribute__((ext_vector_type(8))) short bf16x8;
typedef __attribute__((ext_vector_type(16))) float f32x16;

__device__ __forceinline__ unsigned short f2b(float f) {
    unsigned int x = __float_as_uint(f);
    x += 0x7fffu + ((x >> 16) & 1u);
    return (unsigned short)(x >> 16);
}
__device__ __forceinline__ float b2f(unsigned short u) {
    return __uint_as_float(((unsigned int)u) << 16);
}

// ---------------------------------------------------------------------------
// Kernel S (round-3 verbatim, known-good): fused fp32->split-bf16 conversion +
// S = X^T X partials (MFMA hi*hi+hi*lo+lo*hi) + column sums + g = hi@Wg+bg.
// ---------------------------------------------------------------------------
__global__ __launch_bounds__(256, 2)
void kS(const float* __restrict__ x, const float* __restrict__ Wg,
        const float* __restrict__ bg, unsigned short* __restrict__ g,
        float* __restrict__ Spart, float* __restrict__ cspart)
{
    __shared__ unsigned int  xsT_hi[C_][36];
    __shared__ unsigned int  xsT_lo[C_][36];
    __shared__ unsigned short xs_hi[CH][136];
    __shared__ unsigned short WgT[F_][136];

    const int tid  = threadIdx.x;
    const int lane = tid & 63;
    const int w    = tid >> 6;
    const int b    = blockIdx.x >> 5;
    const int sp   = blockIdx.x & 31;

    for (int i = tid; i < C_*F_; i += 256) {
        int c = i >> 6, f = i & 63;
        WgT[f][c] = f2b(Wg[i]);
    }

    const float* xb = x + ((size_t)b * N_ + (size_t)sp * RPB) * C_;
    unsigned short* gb = g + ((size_t)b * N_ + (size_t)sp * RPB) * F_;

    const int rowA = lane & 31;
    const int kgrp = (lane >> 5) * 8;
    const int c1b  = (w & 1) * 64;
    const int c2b  = (w >> 1) * 64;
    const int nbG  = (w & 1) * 32;
    const int fbG  = (w >> 1) * 32;

    const float bgl = bg[fbG + rowA];

    f32x16 accS[2][2];
    #pragma unroll
    for (int ti = 0; ti < 2; ++ti)
        #pragma unroll
        for (int tj = 0; tj < 2; ++tj)
            #pragma unroll
            for (int e = 0; e < 16; ++e) accS[ti][tj][e] = 0.f;
    float csum = 0.f;

    for (int ch = 0; ch < RPB/CH; ++ch) {
        const float* xc = xb + (size_t)ch * CH * C_;
        #pragma unroll
        for (int p = 0; p < 4; ++p) {
            const int idx = tid + 256*p;
            const int np  = idx & 31;
            const int c4  = (idx >> 5) * 4;
            const float* r0 = xc + (size_t)(2*np) * C_ + c4;
            float4 a = *(const float4*)r0;
            float4 q = *(const float4*)(r0 + C_);
            unsigned short ha0 = f2b(a.x), ha1 = f2b(a.y), ha2 = f2b(a.z), ha3 = f2b(a.w);
            unsigned short hb0 = f2b(q.x), hb1 = f2b(q.y), hb2 = f2b(q.z), hb3 = f2b(q.w);
            unsigned short la0 = f2b(a.x - b2f(ha0)), la1 = f2b(a.y - b2f(ha1));
            unsigned short la2 = f2b(a.z - b2f(ha2)), la3 = f2b(a.w - b2f(ha3));
            unsigned short lb0 = f2b(q.x - b2f(hb0)), lb1 = f2b(q.y - b2f(hb1));
            unsigned short lb2 = f2b(q.z - b2f(hb2)), lb3 = f2b(q.w - b2f(hb3));
            if (p == 0) __syncthreads();   // prior chunk's readers done
            xsT_hi[c4+0][np] = (unsigned)ha0 | ((unsigned)hb0 << 16);
            xsT_hi[c4+1][np] = (unsigned)ha1 | ((unsigned)hb1 << 16);
            xsT_hi[c4+2][np] = (unsigned)ha2 | ((unsigned)hb2 << 16);
            xsT_hi[c4+3][np] = (unsigned)ha3 | ((unsigned)hb3 << 16);
            xsT_lo[c4+0][np] = (unsigned)la0 | ((unsigned)lb0 << 16);
            xsT_lo[c4+1][np] = (unsigned)la1 | ((unsigned)lb1 << 16);
            xsT_lo[c4+2][np] = (unsigned)la2 | ((unsigned)lb2 << 16);
            xsT_lo[c4+3][np] = (unsigned)la3 | ((unsigned)lb3 << 16);
            ushort4 u0; u0.x = ha0; u0.y = ha1; u0.z = ha2; u0.w = ha3;
            ushort4 u1; u1.x = hb0; u1.y = hb1; u1.z = hb2; u1.w = hb3;
            *(ushort4*)&xs_hi[2*np  ][c4] = u0;
            *(ushort4*)&xs_hi[2*np+1][c4] = u1;
        }
        __syncthreads();

        if (tid < C_) {
            #pragma unroll 8
            for (int npp = 0; npp < 32; ++npp) {
                unsigned int h = xsT_hi[tid][npp];
                unsigned int l = xsT_lo[tid][npp];
                csum += b2f((unsigned short)(h & 0xffffu)) + b2f((unsigned short)(h >> 16))
                      + b2f((unsigned short)(l & 0xffffu)) + b2f((unsigned short)(l >> 16));
            }
        }

        #pragma unroll
        for (int ks = 0; ks < 4; ++ks) {
            const int kn = ks*16 + kgrp;
            bf16x8 Ah[2], Al[2], Bh[2], Bl[2];
            #pragma unroll
            for (int t = 0; t < 2; ++t) {
                const unsigned short* rAh = (const unsigned short*)&xsT_hi[c1b + 32*t + rowA][0];
                const unsigned short* rAl = (const unsigned short*)&xsT_lo[c1b + 32*t + rowA][0];
                Ah[t] = *(const bf16x8*)(rAh + kn);
                Al[t] = *(const bf16x8*)(rAl + kn);
                const unsigned short* rBh = (const unsigned short*)&xsT_hi[c2b + 32*t + rowA][0];
                const unsigned short* rBl = (const unsigned short*)&xsT_lo[c2b + 32*t + rowA][0];
                Bh[t] = *(const bf16x8*)(rBh + kn);
                Bl[t] = *(const bf16x8*)(rBl + kn);
            }
            #pragma unroll
            for (int ti = 0; ti < 2; ++ti)
                #pragma unroll
                for (int tj = 0; tj < 2; ++tj) {
                    accS[ti][tj] = __builtin_amdgcn_mfma_f32_32x32x16_bf16(Ah[ti], Bh[tj], accS[ti][tj], 0, 0, 0);
                    accS[ti][tj] = __builtin_amdgcn_mfma_f32_32x32x16_bf16(Ah[ti], Bl[tj], accS[ti][tj], 0, 0, 0);
                    accS[ti][tj] = __builtin_amdgcn_mfma_f32_32x32x16_bf16(Al[ti], Bh[tj], accS[ti][tj], 0, 0, 0);
                }
        }

        {
            f32x16 aG;
            #pragma unroll
            for (int e = 0; e < 16; ++e) aG[e] = 0.f;
            #pragma unroll
            for (int ks = 0; ks < 8; ++ks) {
                bf16x8 av = *(const bf16x8*)&xs_hi[nbG + rowA][ks*16 + kgrp];
                bf16x8 wv = *(const bf16x8*)&WgT [fbG + rowA][ks*16 + kgrp];
                aG = __builtin_amdgcn_mfma_f32_32x32x16_bf16(av, wv, aG, 0, 0, 0);
            }
            const int fcol = fbG + (lane & 31);
            #pragma unroll
            for (int r = 0; r < 16; ++r) {
                int nloc = (r & 3) + 8*(r >> 2) + 4*(lane >> 5);
                int n = ch*CH + nbG + nloc;
                gb[(size_t)n * F_ + fcol] = f2b(aG[r] + bgl);
            }
        }
        __syncthreads();
    }

    float* so = Spart + (size_t)(b * SPLITS + sp) * (size_t)(C_ * C_);
    #pragma unroll
    for (int ti = 0; ti < 2; ++ti)
        #pragma unroll
        for (int tj = 0; tj < 2; ++tj)
            #pragma unroll
            for (int r = 0; r < 16; ++r) {
                int c1 = c1b + 32*ti + (r & 3) + 8*(r >> 2) + 4*(lane >> 5);
                int c2 = c2b + 32*tj + (lane & 31);
                so[(size_t)c1 * C_ + c2] = accS[ti][tj][r];
            }
    if (tid < C_)
        cspart[(size_t)(b * SPLITS + sp) * C_ + tid] = csum;
}

// ---------------------------------------------------------------------------
// Kernel R: reduce Spart over splits -> Sred ; cspart -> csred. Pure BW.
// ---------------------------------------------------------------------------
__global__ __launch_bounds__(256, 8)
void kR(const float* __restrict__ Spart, const float* __restrict__ cspart,
        float* __restrict__ Sred, float* __restrict__ csred)
{
    const int b = blockIdx.x >> 4;
    const int r = blockIdx.x & 15;
    const int f4 = r*256 + threadIdx.x;
    const float4* base = (const float4*)(Spart + (size_t)b * SPLITS * C_ * C_);
    float sx=0.f, sy=0.f, sz=0.f, sw=0.f;
    #pragma unroll 4
    for (int sp = 0; sp < SPLITS; ++sp) {
        float4 v = base[(size_t)sp * (C_*C_/4) + f4];
        sx += v.x; sy += v.y; sz += v.z; sw += v.w;
    }
    ((float4*)(Sred + (size_t)b * C_ * C_))[f4] = make_float4(sx, sy, sz, sw);

    if (r == 0 && threadIdx.x < C_) {
        float c = 0.f;
        #pragma unroll 4
        for (int sp = 0; sp < SPLITS; ++sp)
            c += cspart[((size_t)b * SPLITS + sp) * C_ + threadIdx.x];
        csred[(size_t)b * C_ + threadIdx.x] = c;
    }
}

// ---------------------------------------------------------------------------
// Kernel T: T1 = S @ Wp (per-batch 128x64, K=128), LDS-staged; also T2 = cs@Wp.
// ---------------------------------------------------------------------------
__global__ __launch_bounds__(256, 2)
void kT(const float* __restrict__ Sred, const float* __restrict__ csred,
        const float* __restrict__ Wp, float* __restrict__ T1buf,
        float* __restrict__ T2buf)
{
    __shared__ float Ss[32][C_];
    __shared__ float Wps[C_][F_];

    const int tid = threadIdx.x;
    const int b = blockIdx.x >> 2;
    const int q = blockIdx.x & 3;

    const float4* sg = (const float4*)(Sred + ((size_t)b * C_ + q*32) * C_);
    for (int t = tid; t < 32*C_/4; t += 256) ((float4*)Ss)[t] = sg[t];
    const float4* wg = (const float4*)Wp;
    for (int t = tid; t < C_*F_/4; t += 256) ((float4*)Wps)[t] = wg[t];
    __syncthreads();

    const int lane = tid & 63;
    const int w    = tid >> 6;

    float acc[8] = {0.f,0.f,0.f,0.f,0.f,0.f,0.f,0.f};
    #pragma unroll 2
    for (int k = 0; k < C_; k += 4) {
        float w0 = Wps[k+0][lane];
        float w1 = Wps[k+1][lane];
        float w2 = Wps[k+2][lane];
        float w3 = Wps[k+3][lane];
        #pragma unroll
        for (int cl = 0; cl < 8; ++cl) {
            float4 sv = *(const float4*)&Ss[w*8 + cl][k];
            float t = acc[cl];
            t = fmaf(sv.x, w0, t);
            t = fmaf(sv.y, w1, t);
            t = fmaf(sv.z, w2, t);
            t = fmaf(sv.w, w3, t);
            acc[cl] = t;
        }
    }
    #pragma unroll
    for (int cl = 0; cl < 8; ++cl) {
        int c = q*32 + w*8 + cl;
        T1buf[((size_t)b * C_ + c) * F_ + lane] = acc[cl];
    }

    if (q == 0 && tid < F_) {
        const float* cv = csred + (size_t)b * C_;
        float s = 0.f;
        for (int k = 0; k < C_; ++k) s = fmaf(cv[k], Wps[k][tid], s);
        T2buf[(size_t)b * F_ + tid] = s;
    }
}

// ---------------------------------------------------------------------------
// Kernel F: fm = Wt^T T1 + bias terms; in-register row softmax -> U.
// ---------------------------------------------------------------------------
__global__ __launch_bounds__(256, 2)
void kF(const float* __restrict__ T1buf, const float* __restrict__ T2buf,
        const float* __restrict__ csred, const float* __restrict__ Wt,
        const float* __restrict__ bt, const float* __restrict__ bp,
        float* __restrict__ U)
{
    __shared__ float T1s[C_][F_];
    __shared__ float Wts[C_][F_];
    __shared__ float csb[C_];
    __shared__ float T2s[F_], T3s[F_], bts[F_], bps[F_];

    const int tid = threadIdx.x;
    const int b = blockIdx.x;

    for (int t = tid; t < C_*F_/4; t += 256) {
        ((float4*)T1s)[t] = ((const float4*)(T1buf + (size_t)b * C_ * F_))[t];
        ((float4*)Wts)[t] = ((const float4*)Wt)[t];
    }
    if (tid < C_) csb[tid] = csred[(size_t)b * C_ + tid];
    if (tid < F_) {
        T2s[tid] = T2buf[(size_t)b * F_ + tid];
        bts[tid] = bt[tid];
        bps[tid] = bp[tid];
    }
    __syncthreads();

    if (tid < F_) {
        float s = 0.f;
        for (int c = 0; c < C_; ++c) s = fmaf(csb[c], Wts[c][tid], s);
        T3s[tid] = s;
    }
    __syncthreads();

    const int lane = tid & 63;
    const int w    = tid >> 6;

    float acc[16];
    #pragma unroll
    for (int r = 0; r < 16; ++r) acc[r] = 0.f;

    #pragma unroll 2
    for (int c = 0; c < C_; ++c) {
        float t1 = T1s[c][lane];
        #pragma unroll
        for (int u = 0; u < 4; ++u) {
            float4 wv = *(const float4*)&Wts[c][w*16 + u*4];
            acc[u*4+0] = fmaf(wv.x, t1, acc[u*4+0]);
            acc[u*4+1] = fmaf(wv.y, t1, acc[u*4+1]);
            acc[u*4+2] = fmaf(wv.z, t1, acc[u*4+2]);
            acc[u*4+3] = fmaf(wv.w, t1, acc[u*4+3]);
        }
    }

    const float bpj = bps[lane];
    const float t2j = T2s[lane];
    #pragma unroll
    for (int r = 0; r < 16; ++r) {
        const int i = w*16 + r;
        float v = acc[r] + T3s[i]*bpj + bts[i]*(t2j + (float)N_ * bpj);
        float m = v;
        #pragma unroll
        for (int o = 32; o; o >>= 1) m = fmaxf(m, __shfl_xor(m, o));
        float e = expf(v - m);
        float s = e;
        #pragma unroll
        for (int o = 32; o; o >>= 1) s += __shfl_xor(s, o);
        U[((size_t)b * F_ + i) * F_ + lane] = e / s;
    }
}

// ---------------------------------------------------------------------------
// Kernel C (MFMA, conservative): per (b,half,w): M1 = G_w @ U ;
// Out = M1^T @ Wo ; bias+BN fused. M1 acc -> A-operand relayout through a
// wave-private LDS strip using f2b bit-packing (no inline asm) and a FULL
// __syncthreads() between write and read phases (no ordering assumptions).
// ---------------------------------------------------------------------------
__global__ __launch_bounds__(256, 2)
void kC(const unsigned short* __restrict__ g, const float* __restrict__ U,
        const float* __restrict__ Wo, const float* __restrict__ bo,
        const float* __restrict__ gamma_, const float* __restrict__ beta_,
        const float* __restrict__ mmean, const float* __restrict__ mvar,
        float* __restrict__ out)
{
    __shared__ __align__(16) unsigned short UT[F_][72];        // UT[j][i] bf16
    __shared__ __align__(16) unsigned short WoT[F_][72];       // WoT[e'][f] bf16
    __shared__ __align__(16) unsigned short M1T[4][32][72];    // per-wave M1^T[j][e]

    const int tid  = threadIdx.x;
    const int lane = tid & 63;
    const int wv   = tid >> 6;
    const int jt   = wv & 1;
    const int et   = wv >> 1;

    const int wgrp = blockIdx.x & 15;
    const int half = (blockIdx.x >> 4) & 1;
    const int b    = blockIdx.x >> 5;

    for (int t = tid; t < 1024; t += 256) {
        const int i  = t >> 4;
        const int j4 = (t & 15) * 4;
        float4 uv = *(const float4*)(U + ((size_t)b * F_ + i) * F_ + j4);
        UT[j4+0][i] = f2b(uv.x); UT[j4+1][i] = f2b(uv.y);
        UT[j4+2][i] = f2b(uv.z); UT[j4+3][i] = f2b(uv.w);
        float4 wo4 = *(const float4*)(Wo + (size_t)i * F_ + j4);
        WoT[j4+0][i] = f2b(wo4.x); WoT[j4+1][i] = f2b(wo4.y);
        WoT[j4+2][i] = f2b(wo4.z); WoT[j4+3][i] = f2b(wo4.w);
    }
    __syncthreads();

    const int rowA = lane & 31;
    const int hi   = lane >> 5;
    const int hi8  = hi * 8;

    bf16x8 Ufr[4], WoFr[4];
    #pragma unroll
    for (int ks = 0; ks < 4; ++ks) {
        Ufr[ks]  = *(const bf16x8*)&UT [32*jt + rowA][16*ks + hi8];
        WoFr[ks] = *(const bf16x8*)&WoT[32*et + rowA][16*ks + hi8];
    }

    const int ep = 32*et + rowA;                 // this lane's output channel
    const float scl = gamma_[ep] * rsqrtf(mvar[ep] + EPSV);
    const float sft = (bo[ep] - mmean[ep]) * scl + beta_[ep];

    const unsigned short* gB = g + ((size_t)b * N_ + (size_t)half * (N_/2)) * F_;
    float* outB = out + (((size_t)b * H_ + half) * W_) * F_ + ep;
    const int w0 = wgrp * 8;

    unsigned short* m1row = &M1T[wv][rowA][0];

    auto gload = [&](bf16x8 (&D)[2][4], int widx) {
        const unsigned short* gw = gB + (size_t)widx * (64*F_) + (size_t)rowA * F_ + hi8;
        #pragma unroll
        for (int ft = 0; ft < 2; ++ft)
            #pragma unroll
            for (int ks = 0; ks < 4; ++ks)
                D[ft][ks] = *(const bf16x8*)(gw + ft*(32*F_) + 16*ks);
    };

    auto body = [&](bf16x8 (&G)[2][4], int widx) {
        f32x16 m0, m1, a2r;
        #pragma unroll
        for (int e = 0; e < 16; ++e) { m0[e] = 0.f; m1[e] = 0.f; a2r[e] = 0.f; }
        #pragma unroll
        for (int ks = 0; ks < 4; ++ks) {
            m0 = __builtin_amdgcn_mfma_f32_32x32x16_bf16(G[0][ks], Ufr[ks], m0, 0, 0, 0);
            m1 = __builtin_amdgcn_mfma_f32_32x32x16_bf16(G[1][ks], Ufr[ks], m1, 0, 0, 0);
        }
        // write M1^T (bf16) to wave-private LDS strip via C/D layout:
        // m0[r] = M1[e = (r&3)+8*(r>>2)+4*hi][j = lane&31]; regs r,r+1 are
        // consecutive e -> one bit-packed u32 store per pair (f2b, no asm).
        #pragma unroll
        for (int r = 0; r < 16; r += 2) {
            const int e0 = (r & 3) + 8*(r >> 2) + 4*hi;
            const unsigned pw0 = (unsigned)f2b(m0[r]) | ((unsigned)f2b(m0[r+1]) << 16);
            *(unsigned int*)(m1row + e0) = pw0;
            const unsigned pw1 = (unsigned)f2b(m1[r]) | ((unsigned)f2b(m1[r+1]) << 16);
            *(unsigned int*)(m1row + 32 + e0) = pw1;
        }
        __syncthreads();   // full fence: all strip writes visible before reads
        // read standard A-frags back (lane m=j=lane&31, k=e=16*ksg+hi8+jj)
        #pragma unroll
        for (int ksg = 0; ksg < 4; ++ksg) {
            bf16x8 af = *(const bf16x8*)(m1row + 16*ksg + hi8);
            a2r = __builtin_amdgcn_mfma_f32_32x32x16_bf16(af, WoFr[ksg], a2r, 0, 0, 0);
        }
        // epilogue: BN + store. a2r: col = e' = lane&31, row = j_local
        float* ow = outB + (size_t)widx * F_ + (size_t)(64*jt + 8*hi) * (W_*F_);
        #pragma unroll
        for (int r = 0; r < 16; ++r) {
            const int off2j = 2*(r & 3) + 16*(r >> 2);   // 2*j within quad
            ow[(size_t)off2j * (W_*F_)] = a2r[r] * scl + sft;
        }
        __syncthreads();   // strip reads done before next body's writes
    };

    bf16x8 GA[2][4], GBf[2][4];
    gload(GA, w0);
    #pragma unroll
    for (int wi = 0; wi < 8; ++wi) {
        if (wi & 1) {
            if (wi < 7) gload(GA, w0 + wi + 1);
            body(GBf, w0 + wi);
        } else {
            if (wi < 7) gload(GBf, w0 + wi + 1);
            body(GA, w0 + wi);
        }
    }
}

extern "C" void kernel_launch(void* const* d_in, const int* in_sizes, int n_in,
                              void* d_out, int out_size, void* d_ws, size_t ws_size,
                              hipStream_t stream)
{
    const float* x  = (const float*)d_in[0];
    const float* Wg = (const float*)d_in[1];
    const float* bg = (const float*)d_in[2];
    const float* Wt = (const float*)d_in[3];
    const float* bt = (const float*)d_in[4];
    const float* Wp = (const float*)d_in[5];
    const float* bp = (const float*)d_in[6];
    const float* Wo = (const float*)d_in[7];
    const float* bo = (const float*)d_in[8];
    const float* ga = (const float*)d_in[9];
    const float* be = (const float*)d_in[10];
    const float* mm = (const float*)d_in[11];
    const float* mv = (const float*)d_in[12];
    float* out = (float*)d_out;

    // ws layout: g 32MiB | Spart 32MiB (T1buf overlays; Spart dead after kR) |
    //            cspart 256KiB | U 256KiB | Sred 1MiB | csred 8KiB | T2buf 4KiB
    char* ws = (char*)d_ws;
    unsigned short* g = (unsigned short*)ws;
    size_t off = (size_t)B_ * N_ * F_ * sizeof(unsigned short);
    float* Spart = (float*)(ws + off);
    float* T1buf = (float*)(ws + off);
    off += (size_t)B_ * SPLITS * C_ * C_ * sizeof(float);
    float* cspart = (float*)(ws + off);
    off += (size_t)B_ * SPLITS * C_ * sizeof(float);
    float* U = (float*)(ws + off);
    off += (size_t)B_ * F_ * F_ * sizeof(float);
    float* Sred = (float*)(ws + off);
    off += (size_t)B_ * C_ * C_ * sizeof(float);
    float* csred = (float*)(ws + off);
    off += (size_t)B_ * C_ * sizeof(float);
    float* T2buf = (float*)(ws + off);

    kS<<<B_ * SPLITS, 256, 0, stream>>>(x, Wg, bg, g, Spart, cspart);
    kR<<<B_ * 16, 256, 0, stream>>>(Spart, cspart, Sred, csred);
    kT<<<B_ * 4, 256, 0, stream>>>(Sred, csred, Wp, T1buf, T2buf);
    kF<<<B_, 256, 0, stream>>>(T1buf, T2buf, csred, Wt, bt, bp, U);
    kC<<<B_ * 2 * (W_/8), 256, 0, stream>>>(g, U, Wo, bo, ga, be, mm, mv, out);
}